// Round 1
// baseline (3880.152 us; speedup 1.0000x reference)
//
#include <hip/hip_runtime.h>
#include <cstdint>

#define DEVINL __device__ __forceinline__

typedef unsigned short u16;
typedef unsigned int u32;
typedef __bf16 bf16x8 __attribute__((ext_vector_type(8)));
typedef float f32x4 __attribute__((ext_vector_type(4)));
typedef u32 u32x4 __attribute__((ext_vector_type(4)));
typedef u16 u16x4 __attribute__((ext_vector_type(4)));

// Problem constants
constexpr int Tn  = 4096;   // B*S tokens
constexpr int Hn  = 4096;
constexpr int NHn = 32;
constexpr int HDn = 128;
constexpr int In  = 11008;
constexpr int Sn  = 2048;
constexpr int Bn  = 2;

// ---------- small helpers ----------
DEVINL u16 f2b(float f) {                      // fp32 -> bf16 RNE
  u32 u = __builtin_bit_cast(u32, f);
  u32 r = 0x7fffu + ((u >> 16) & 1u);
  return (u16)((u + r) >> 16);
}
DEVINL float b2f(u16 v) { return __builtin_bit_cast(float, (u32)v << 16); }

DEVINL void gl_lds16(const void* g, void* l) {
  // global -> LDS direct copy, 16B per lane; LDS dest must be wave-uniform base.
  __builtin_amdgcn_global_load_lds(
      (const __attribute__((address_space(1))) u32*)(uintptr_t)g,
      (__attribute__((address_space(3))) u32*)(u32)(uintptr_t)l,
      16, 0, 0);
}

// ---------- fp32 (K,N) -> bf16 (N,K) transpose-convert ----------
__global__ __launch_bounds__(256) void conv_t_k(const float* __restrict__ in,
                                                u16* __restrict__ out,
                                                int K, int N) {
  __shared__ float tile[64][65];
  const int k0 = blockIdx.y * 64, n0 = blockIdx.x * 64;
  const int rt = threadIdx.x >> 4, ct = threadIdx.x & 15;
#pragma unroll
  for (int r = 0; r < 4; ++r) {
    const int row = rt + r * 16;
    const f32x4 v = *(const f32x4*)(in + (size_t)(k0 + row) * N + n0 + ct * 4);
    tile[row][ct * 4 + 0] = v[0]; tile[row][ct * 4 + 1] = v[1];
    tile[row][ct * 4 + 2] = v[2]; tile[row][ct * 4 + 3] = v[3];
  }
  __syncthreads();
#pragma unroll
  for (int r = 0; r < 4; ++r) {
    const int nrow = rt + r * 16;
    u16x4 o;
    o[0] = f2b(tile[ct * 4 + 0][nrow]); o[1] = f2b(tile[ct * 4 + 1][nrow]);
    o[2] = f2b(tile[ct * 4 + 2][nrow]); o[3] = f2b(tile[ct * 4 + 3][nrow]);
    *(u16x4*)(out + (size_t)(n0 + nrow) * K + k0 + ct * 4) = o;
  }
}

// ---------- fused (optional add) + RMSNorm: fp32 in -> bf16 normed (+ fp32 sum) ----------
template <bool ADD>
__global__ __launch_bounds__(256) void rmsnorm_k(const float* __restrict__ x,
                                                 const float* __restrict__ y,
                                                 const float* __restrict__ w,
                                                 float* __restrict__ sum_out,
                                                 u16* __restrict__ nout) {
  const int t = blockIdx.x;
  const f32x4* x4 = (const f32x4*)(x + (size_t)t * Hn);
  __shared__ float red[4];
  f32x4 vals[4];
  float ss = 0.f;
#pragma unroll
  for (int i = 0; i < 4; ++i) {
    const int c = threadIdx.x + i * 256;
    f32x4 v = x4[c];
    if constexpr (ADD) {
      const f32x4 u = ((const f32x4*)(y + (size_t)t * Hn))[c];
      v = v + u;
      ((f32x4*)(sum_out + (size_t)t * Hn))[c] = v;
    }
    vals[i] = v;
    ss += v[0] * v[0] + v[1] * v[1] + v[2] * v[2] + v[3] * v[3];
  }
#pragma unroll
  for (int off = 1; off < 64; off <<= 1) ss += __shfl_xor(ss, off, 64);
  if ((threadIdx.x & 63) == 0) red[threadIdx.x >> 6] = ss;
  __syncthreads();
  const float rr = rsqrtf((red[0] + red[1] + red[2] + red[3]) * (1.f / Hn) + 1e-6f);
#pragma unroll
  for (int i = 0; i < 4; ++i) {
    const int c = threadIdx.x + i * 256;
    const f32x4 wv = ((const f32x4*)w)[c];
    u16x4 o;
    o[0] = f2b(vals[i][0] * rr * wv[0]); o[1] = f2b(vals[i][1] * rr * wv[1]);
    o[2] = f2b(vals[i][2] * rr * wv[2]); o[3] = f2b(vals[i][3] * rr * wv[3]);
    *(u16x4*)(nout + (size_t)t * Hn + c * 4) = o;
  }
}

// ---------- m97-style GEMM: C[M,N] = A[M,K](bf16) x Bt[N,K]^T(bf16), fp32 accum ----------
// EPI 0: store bf16 ; EPI 1: store fp32 ; EPI 2: store fp32 = acc + resid
template <int EPI>
__global__ __launch_bounds__(256) void gemm_bt(const u16* __restrict__ A,
                                               const u16* __restrict__ Bt,
                                               void* __restrict__ C,
                                               const float* __restrict__ resid,
                                               int M, int N, int K) {
  __shared__ __align__(16) u16 As[128 * 32];
  __shared__ __align__(16) u16 Bs[128 * 32];
  const int tid = threadIdx.x;
  const int lane = tid & 63, wave = tid >> 6;
  const int quad = lane >> 4, l16 = lane & 15;
  const int m0 = blockIdx.y * 128, n0 = blockIdx.x * 128;
  const int wr = (wave >> 1) * 64, wc = (wave & 1) * 64;
  const u16* Ag = A + (size_t)m0 * K;
  const u16* Bg = Bt + (size_t)n0 * K;
  f32x4 acc[4][4];
  const f32x4 fz = {0.f, 0.f, 0.f, 0.f};
#pragma unroll
  for (int i = 0; i < 4; ++i)
#pragma unroll
    for (int j = 0; j < 4; ++j) acc[i][j] = fz;

  for (int k0 = 0; k0 < K; k0 += 32) {
#pragma unroll
    for (int r = 0; r < 2; ++r) {
      const int cb = r * 256 + wave * 64;       // wave-uniform chunk base
      const int c = cb + lane;                  // chunk: row=c>>2, kpart=c&3
      const size_t goff = (size_t)(c >> 2) * K + (k0 + (c & 3) * 8);
      gl_lds16(Ag + goff, &As[cb * 8]);
      gl_lds16(Bg + goff, &Bs[cb * 8]);
    }
    __syncthreads();
    bf16x8 af[4], bfv[4];
#pragma unroll
    for (int i = 0; i < 4; ++i)
      af[i] = *(const bf16x8*)&As[(wr + i * 16 + l16) * 32 + quad * 8];
#pragma unroll
    for (int j = 0; j < 4; ++j)
      bfv[j] = *(const bf16x8*)&Bs[(wc + j * 16 + l16) * 32 + quad * 8];
#pragma unroll
    for (int i = 0; i < 4; ++i)
#pragma unroll
      for (int j = 0; j < 4; ++j)
        acc[i][j] = __builtin_amdgcn_mfma_f32_16x16x32_bf16(af[i], bfv[j], acc[i][j], 0, 0, 0);
    __syncthreads();
  }
#pragma unroll
  for (int i = 0; i < 4; ++i) {
#pragma unroll
    for (int j = 0; j < 4; ++j) {
      const int col = n0 + wc + j * 16 + l16;
#pragma unroll
      for (int r = 0; r < 4; ++r) {
        const int row = m0 + wr + i * 16 + quad * 4 + r;
        const size_t idx = (size_t)row * N + col;
        const float v = acc[i][j][r];
        if constexpr (EPI == 0) ((u16*)C)[idx] = f2b(v);
        else if constexpr (EPI == 1) ((float*)C)[idx] = v;
        else ((float*)C)[idx] = v + resid[idx];
      }
    }
  }
}

// ---------- RoPE in-place on bf16 qkv (q and k slots) ----------
__global__ __launch_bounds__(256) void rope_k(u16* __restrict__ qkv,
                                              const float* __restrict__ cb,
                                              const float* __restrict__ sb) {
  const int idx = blockIdx.x * 256 + threadIdx.x;   // T*NH*64 threads
  const int d = idx & 63;
  const int h = (idx >> 6) & 31;
  const int t = idx >> 11;
  const float c = cb[t * 64 + d], s = sb[t * 64 + d];
  u16* p = qkv + (size_t)t * (3 * Hn) + h * HDn;
#pragma unroll
  for (int w2 = 0; w2 < 2; ++w2) {                  // q slot, then k slot
    const float x1 = b2f(p[d]), x2 = b2f(p[d + 64]);
    p[d] = f2b(x1 * c - x2 * s);
    p[d + 64] = f2b(x1 * s + x2 * c);
    p += Hn;
  }
}

// ---------- causal flash attention ----------
// grid: (S/64, B*NH); 256 threads = 4 waves, wave w owns query rows q0+w*16..+15
__global__ __launch_bounds__(256) void flash_attn(const u16* __restrict__ qkv,
                                                  u16* __restrict__ outp) {
  __shared__ __align__(16) u16 Ks[64 * 136];   // [key][dim], stride 136 (pad 8)
  __shared__ __align__(16) u16 Vt[128 * 72];   // [dim][key], stride 72
  __shared__ __align__(16) u16 Ps[4][16 * 72]; // per-wave P, [row][key], stride 72
  const int tid = threadIdx.x;
  const int lane = tid & 63, wave = tid >> 6;
  const int quad = lane >> 4, l16 = lane & 15;
  const int bh = blockIdx.y, b = bh >> 5, h = bh & 31;
  const int q0 = blockIdx.x * 64;
  const float scale = 0.088388347648318447f;   // 1/sqrt(128)
  const size_t tstride = 3 * Hn;
  const u16* base = qkv + (size_t)b * Sn * tstride + h * HDn;
  const f32x4 fz = {0.f, 0.f, 0.f, 0.f};

  bf16x8 qf[4];
  {
    const u16* qp = base + (size_t)(q0 + wave * 16 + l16) * tstride;
#pragma unroll
    for (int kc = 0; kc < 4; ++kc) qf[kc] = *(const bf16x8*)(qp + kc * 32 + quad * 8);
  }
  float m_i[4], l_i[4];
  f32x4 o_acc[8];
#pragma unroll
  for (int r = 0; r < 4; ++r) { m_i[r] = -3.0e38f; l_i[r] = 0.f; }
#pragma unroll
  for (int ob = 0; ob < 8; ++ob) o_acc[ob] = fz;

  const int ntiles = blockIdx.x + 1;
  for (int kt = 0; kt < ntiles; ++kt) {
    const int k0 = kt * 64;
    // stage K tile [64][128]
#pragma unroll
    for (int r = 0; r < 4; ++r) {
      const int c = r * 256 + tid;
      const int key = c >> 4, part = c & 15;
      *(u32x4*)&Ks[key * 136 + part * 8] =
          *(const u32x4*)(base + Hn + (size_t)(k0 + key) * tstride + part * 8);
    }
    // stage V transposed [128][64]
#pragma unroll
    for (int r = 0; r < 4; ++r) {
      const int c = r * 256 + tid;
      const int key = c & 63, grp = c >> 6;
      u32x4 vv = *(const u32x4*)(base + 2 * Hn + (size_t)(k0 + key) * tstride + grp * 8);
      const u16* pv = (const u16*)&vv;
#pragma unroll
      for (int i2 = 0; i2 < 8; ++i2) Vt[(grp * 8 + i2) * 72 + key] = pv[i2];
    }
    __syncthreads();

    // S = Q K^T  (4 col-blocks of 16 keys)
    f32x4 sa[4];
#pragma unroll
    for (int jb = 0; jb < 4; ++jb) {
      f32x4 a = fz;
#pragma unroll
      for (int kc = 0; kc < 4; ++kc) {
        const bf16x8 kf = *(const bf16x8*)&Ks[(jb * 16 + l16) * 136 + kc * 32 + quad * 8];
        a = __builtin_amdgcn_mfma_f32_16x16x32_bf16(qf[kc], kf, a, 0, 0, 0);
      }
      sa[jb] = a;
    }

    const bool diag = (kt == blockIdx.x);
#pragma unroll
    for (int r = 0; r < 4; ++r) {
      const int row = q0 + wave * 16 + quad * 4 + r;
      float mx = -3.0e38f;
      float sv[4];
#pragma unroll
      for (int jb = 0; jb < 4; ++jb) {
        float v = sa[jb][r] * scale;
        if (diag && (k0 + jb * 16 + l16) > row) v = -3.0e38f;
        sv[jb] = v;
        mx = fmaxf(mx, v);
      }
#pragma unroll
      for (int off = 1; off < 16; off <<= 1) mx = fmaxf(mx, __shfl_xor(mx, off, 64));
      const float mnew = fmaxf(m_i[r], mx);
      const float alpha = __expf(m_i[r] - mnew);
      float rs = 0.f;
#pragma unroll
      for (int jb = 0; jb < 4; ++jb) {
        const float p = __expf(sv[jb] - mnew);
        sa[jb][r] = p;
        rs += p;
      }
#pragma unroll
      for (int off = 1; off < 16; off <<= 1) rs += __shfl_xor(rs, off, 64);
      l_i[r] = l_i[r] * alpha + rs;
      m_i[r] = mnew;
#pragma unroll
      for (int ob = 0; ob < 8; ++ob) o_acc[ob][r] = o_acc[ob][r] * alpha;
    }

    // P: C-layout -> LDS -> A-layout (per-wave buffer; DS ops in-order within wave)
    u16* P = &Ps[wave][0];
#pragma unroll
    for (int jb = 0; jb < 4; ++jb)
#pragma unroll
      for (int r = 0; r < 4; ++r)
        P[(quad * 4 + r) * 72 + jb * 16 + l16] = f2b(sa[jb][r]);
    asm volatile("s_waitcnt lgkmcnt(0)" ::: "memory");

    // O += P V
#pragma unroll
    for (int kc2 = 0; kc2 < 2; ++kc2) {
      const bf16x8 pf = *(const bf16x8*)&P[l16 * 72 + kc2 * 32 + quad * 8];
#pragma unroll
      for (int ob = 0; ob < 8; ++ob) {
        const bf16x8 vf = *(const bf16x8*)&Vt[(ob * 16 + l16) * 72 + kc2 * 32 + quad * 8];
        o_acc[ob] = __builtin_amdgcn_mfma_f32_16x16x32_bf16(pf, vf, o_acc[ob], 0, 0, 0);
      }
    }
    __syncthreads();
  }

#pragma unroll
  for (int ob = 0; ob < 8; ++ob)
#pragma unroll
    for (int r = 0; r < 4; ++r) {
      const int row = q0 + wave * 16 + quad * 4 + r;
      outp[(size_t)(b * Sn + row) * Hn + h * HDn + ob * 16 + l16] = f2b(o_acc[ob][r] / l_i[r]);
    }
}

// ---------- SiLU(gate) * up ----------
__global__ __launch_bounds__(256) void silu_mul_k(const u16* __restrict__ gu,
                                                  u16* __restrict__ act) {
  const int chunk = blockIdx.x * 256 + threadIdx.x;  // T * (I/8) chunks
  const int t = chunk / 1376;                        // 11008/8
  const int i0 = (chunk - t * 1376) * 8;
  const u16* g = gu + (size_t)t * (2 * In) + i0;
  u32x4 gv = *(const u32x4*)g;
  u32x4 uv = *(const u32x4*)(g + In);
  const u16* gp = (const u16*)&gv;
  const u16* up = (const u16*)&uv;
  u16 ov[8];
#pragma unroll
  for (int i = 0; i < 8; ++i) {
    const float x = b2f(gp[i]), y = b2f(up[i]);
    ov[i] = f2b((x / (1.f + __expf(-x))) * y);
  }
  *(u32x4*)(act + (size_t)t * In + i0) = *(const u32x4*)ov;
}

// ---------- launch ----------
extern "C" void kernel_launch(void* const* d_in, const int* in_sizes, int n_in,
                              void* d_out, int out_size, void* d_ws, size_t ws_size,
                              hipStream_t stream) {
  const float* hs    = (const float*)d_in[0];
  const float* resid = (const float*)d_in[1];
  const float* cosb  = (const float*)d_in[2];
  const float* sinb  = (const float*)d_in[3];
  const float* wqkv  = (const float*)d_in[4];
  const float* wo    = (const float*)d_in[5];
  const float* wgu   = (const float*)d_in[6];
  const float* wd    = (const float*)d_in[7];
  const float* ln1   = (const float*)d_in[8];
  const float* ln2   = (const float*)d_in[9];

  float* out_mlp = (float*)d_out;
  float* res2    = out_mlp + (size_t)Tn * Hn;

  char* wsb = (char*)d_ws;
  size_t off = 0;
  auto take = [&](size_t bytes) {
    void* p = wsb + off;
    off += (bytes + 255) & ~(size_t)255;
    return p;
  };
  u16*   wbuf  = (u16*)take((size_t)(2 * In) * Hn * 2);   // 180.4 MB: largest W^T
  float* res1  = (float*)take((size_t)Tn * Hn * 4);       // 67.1 MB
  u16*   nrm   = (u16*)take((size_t)Tn * Hn * 2);         // 33.6 MB
  u16*   qkv   = (u16*)take((size_t)Tn * 3 * Hn * 2);     // 100.7 MB
  u16*   attn  = (u16*)take((size_t)Tn * Hn * 2);         // 33.6 MB
  u16*   gu    = (u16*)take((size_t)Tn * 2 * In * 2);     // 180.4 MB
  u16*   act   = qkv;                                     // reuse (free after attention)

  // 1) res1 = hs + residual ; normed1 = rmsnorm(res1, ln1)
  rmsnorm_k<true><<<Tn, 256, 0, stream>>>(hs, resid, ln1, res1, nrm);
  // 2) w_qkv^T -> bf16
  conv_t_k<<<dim3(3 * Hn / 64, Hn / 64), 256, 0, stream>>>(wqkv, wbuf, Hn, 3 * Hn);
  // 3) qkv = normed1 @ w_qkv   (bf16 out)
  gemm_bt<0><<<dim3(3 * Hn / 128, Tn / 128), 256, 0, stream>>>(nrm, wbuf, qkv, nullptr, Tn, 3 * Hn, Hn);
  // 4) RoPE in-place on q,k
  rope_k<<<(Tn * NHn * 64) / 256, 256, 0, stream>>>(qkv, cosb, sinb);
  // 5) causal flash attention -> attn (T,H) bf16
  flash_attn<<<dim3(Sn / 64, Bn * NHn), 256, 0, stream>>>(qkv, attn);
  // 6) w_o^T -> bf16
  conv_t_k<<<dim3(Hn / 64, Hn / 64), 256, 0, stream>>>(wo, wbuf, Hn, Hn);
  // 7) res2 = attn @ w_o + res1   (fp32, into d_out second half)
  gemm_bt<2><<<dim3(Hn / 128, Tn / 128), 256, 0, stream>>>(attn, wbuf, res2, res1, Tn, Hn, Hn);
  // 8) normed2 = rmsnorm(res2, ln2)
  rmsnorm_k<false><<<Tn, 256, 0, stream>>>(res2, nullptr, ln2, nullptr, nrm);
  // 9) w_gate_up^T -> bf16
  conv_t_k<<<dim3(2 * In / 64, Hn / 64), 256, 0, stream>>>(wgu, wbuf, Hn, 2 * In);
  // 10) gu = normed2 @ w_gate_up (bf16 out)
  gemm_bt<0><<<dim3(2 * In / 128, Tn / 128), 256, 0, stream>>>(nrm, wbuf, gu, nullptr, Tn, 2 * In, Hn);
  // 11) act = silu(gate) * up
  silu_mul_k<<<(Tn * In / 8) / 256, 256, 0, stream>>>(gu, act);
  // 12) w_down^T -> bf16
  conv_t_k<<<dim3(Hn / 64, In / 64), 256, 0, stream>>>(wd, wbuf, In, Hn);
  // 13) mlp = act @ w_down (fp32, into d_out first half)
  gemm_bt<1><<<dim3(Hn / 128, Tn / 128), 256, 0, stream>>>(act, wbuf, out_mlp, nullptr, Tn, Hn, In);
}